// Round 20
// baseline (55.253 us; speedup 1.0000x reference)
//
#include <hip/hip_runtime.h>

// Local 8x8 window autocorrelation, stride 4.
// x: (B, C, H, W) fp32 -> out: (B, C, nH, nW, KH, KW) fp32
// out[n, dy, dx] = sum_{i,j} p[i+dy-4][j+dx-4] * p[i][j]  (zero outside window)
//
// R20: TWO WINDOWS PER THREAD, INTERLEAVED (ILP across windows).
// Plateau ledger: stores byte-exact (R6+), spill solved, occupancy road
// closed (R15-R18), generation-overlap null (R12), sched_barrier null (R19).
// Untested mechanism: every prior kernel gives a thread ONE dependency
// chain - each r-step's FMAs consume that step's loaded row, exposing
// ~120-225cyc L1/L2 latency per step. Interleaving two independent windows
// doubles the chains at the same residency class: win-A's load in flight
// while win-B's 48-FMA block issues.
//   wave 0 (role A): d=0,d=1+c50 for windows k and k+64 (ring-3/window)
//   wave 1 (role B): d=2,3,4+c60,c70 (cur ring-2 + serial aux reload/window)
// Live sets ~95 (A) / ~110-125 (B) <= launch_bounds(128,2) cap of 128
// (calibrated: cap = 256/w; R3/R14/R16/R18). Per-window numerics and
// summation order identical to R12 -> absmax unchanged (0.0625).
// Staging: two phases of 64 windows (16.6KB slab), 1KB full-sector wave
// stores (partial-sector = 3-4.7x: R1/R4). Bijective XCD swizzle (m204
// general form; 2116 % 8 = 4).

constexpr int KH = 8, KW = 8, SH = 4, SW = 4;
constexpr int B = 8, C = 64, H = 96, W = 96;
constexpr int nH = (H - KH) / SH + 1;  // 23
constexpr int nW = (W - KW) / SW + 1;  // 23
constexpr int NWIN = B * C * nH * nW;  // 270848 = 128 * 2116
constexpr int TPB = 128;
constexpr int WPB = 128;               // windows per block (2 per thread-slot)
constexpr int OSTRIDE = 65;            // 64 floats + 1 pad
constexpr int NBLK = NWIN / WPB;       // 2116
constexpr int NXCD = 8;
constexpr int SWZ_Q = NBLK / NXCD;     // 264
constexpr int SWZ_R = NBLK % NXCD;     // 4

__global__ __launch_bounds__(TPB, 2) void
local_autocorr_kernel(const float* __restrict__ x, float* __restrict__ out) {
    __shared__ float lds[64 * OSTRIDE];  // 16640 B

    const int tid  = threadIdx.x;
    const int role = tid >> 6;           // wave 0 = A, wave 1 = B
    const int k    = tid & 63;

    // Bijective XCD swizzle, general form (nwg % 8 != 0).
    const int bid = (int)blockIdx.x;
    const int xcd = bid & 7;
    const int idx = bid >> 3;
    const int blk = (xcd < SWZ_R ? xcd * (SWZ_Q + 1)
                                 : SWZ_R * (SWZ_Q + 1) + (xcd - SWZ_R) * SWZ_Q) + idx;

    const int n0 = blk * WPB + k;        // window 0: slots 0..63
    const int n1 = n0 + 64;              // window 1: slots 64..127

    const int w0  = n0 % nW;  const int t0 = n0 / nW;
    const int h0  = t0 % nH;  const int bc0 = t0 / nH;
    const int w1  = n1 % nW;  const int t1 = n1 / nW;
    const int h1  = t1 % nH;  const int bc1 = t1 / nH;

    const float* xp0 = x + ((size_t)bc0 * H + (size_t)h0 * SH) * W + (size_t)w0 * SW;
    const float* xp1 = x + ((size_t)bc1 * H + (size_t)h1 * SH) * W + (size_t)w1 * SW;

#define LOADROW(dst, xp, ri)                                                          \
    {                                                                                 \
        const float4 lo_ = *reinterpret_cast<const float4*>((xp) + (size_t)(ri)*W);   \
        const float4 hi_ = *reinterpret_cast<const float4*>((xp) + (size_t)(ri)*W+4); \
        dst[0]=lo_.x; dst[1]=lo_.y; dst[2]=lo_.z; dst[3]=lo_.w;                       \
        dst[4]=hi_.x; dst[5]=hi_.y; dst[6]=hi_.z; dst[7]=hi_.w;                       \
    }

    // acc[dx] += A[j+OX] * B[j], static j-guards (48 FMA).
#define FMABLK(ACC, AROW, BROW)                                                       \
    {                                                                                 \
        _Pragma("unroll")                                                             \
        for (int dx = 0; dx < 8; ++dx) {                                              \
            const int OX = dx - 4;                                                    \
            _Pragma("unroll")                                                         \
            for (int j = 0; j < 8; ++j) {                                             \
                if (j + OX < 0 || j + OX >= 8) continue; /* static DCE */             \
                ACC[dx] = fmaf(AROW[j + OX], BROW[j], ACC[dx]);                       \
            }                                                                         \
        }                                                                             \
    }

    // folded cell (4+d, 0): CC += sum_{j=0..3} BROW[j] * AROW[j+4]
#define CELLF(CC, AROW, BROW)                                                         \
    {                                                                                 \
        CC = fmaf(BROW[0], AROW[4], CC); CC = fmaf(BROW[1], AROW[5], CC);             \
        CC = fmaf(BROW[2], AROW[6], CC); CC = fmaf(BROW[3], AROW[7], CC);             \
    }

    // Accumulators for both windows (role-specific subsets used).
    float a0w0[8], a1w0[8], a0w1[8], a1w1[8];            // role A: d0, d1
    float a2w0[8], a3w0[8], a4w0[8], a2w1[8], a3w1[8], a4w1[8];  // role B
    float c50w0 = 0.f, c50w1 = 0.f;
    float c60w0 = 0.f, c70w0 = 0.f, c60w1 = 0.f, c70w1 = 0.f;

    if (role == 0) {
        // ===== role A: d=0 (dy=4), d=1 (dy=3) + c50. ring-3 per window. =====
#pragma unroll
        for (int dx = 0; dx < 8; ++dx) {
            a0w0[dx] = 0.f; a1w0[dx] = 0.f; a0w1[dx] = 0.f; a1w1[dx] = 0.f;
        }
        float r0_[3][8], r1_[3][8];
        LOADROW(r0_[0], xp0, 0) LOADROW(r1_[0], xp1, 0)
        LOADROW(r0_[1], xp0, 1) LOADROW(r1_[1], xp1, 1)
        // r = 0: d0 only (rows loaded just above).
        FMABLK(a0w0, r0_[0], r0_[0])
        FMABLK(a0w1, r1_[0], r1_[0])
#pragma unroll
        for (int r = 1; r < 8; ++r) {
            if (r < 7) { LOADROW(r0_[(r + 1) % 3], xp0, r + 1)
                         LOADROW(r1_[(r + 1) % 3], xp1, r + 1) }
            // d0 on row r (loaded last step -> latency covered)
            FMABLK(a0w0, r0_[r % 3], r0_[r % 3])
            FMABLK(a0w1, r1_[r % 3], r1_[r % 3])
            // d1: A = row r-1, B = row r (+ folded cell (5,0))
            FMABLK(a1w0, r0_[(r - 1) % 3], r0_[r % 3])
            CELLF(c50w0, r0_[(r - 1) % 3], r0_[r % 3])
            FMABLK(a1w1, r1_[(r - 1) % 3], r1_[r % 3])
            CELLF(c50w1, r1_[(r - 1) % 3], r1_[r % 3])
        }
    } else {
        // ===== role B: d=2,3,4 + c60,c70. cur ring-2 + serial aux. =====
#pragma unroll
        for (int dx = 0; dx < 8; ++dx) {
            a2w0[dx] = 0.f; a3w0[dx] = 0.f; a4w0[dx] = 0.f;
            a2w1[dx] = 0.f; a3w1[dx] = 0.f; a4w1[dx] = 0.f;
        }
        float cc0[2][8], cc1[2][8], aux0[8], aux1[8];
        LOADROW(cc0[0], xp0, 2) LOADROW(cc1[0], xp1, 2)
#pragma unroll
        for (int r = 2; r < 8; ++r) {
            if (r < 7) { LOADROW(cc0[(r + 1) & 1], xp0, r + 1)
                         LOADROW(cc1[(r + 1) & 1], xp1, r + 1) }
            // d=2: A = row r-2 (aux reload, L1-hot), B = cur
            LOADROW(aux0, xp0, r - 2) LOADROW(aux1, xp1, r - 2)
            FMABLK(a2w0, aux0, cc0[r & 1]) CELLF(c60w0, aux0, cc0[r & 1])
            FMABLK(a2w1, aux1, cc1[r & 1]) CELLF(c60w1, aux1, cc1[r & 1])
            // d=3
            if (r >= 3) {
                LOADROW(aux0, xp0, r - 3) LOADROW(aux1, xp1, r - 3)
                FMABLK(a3w0, aux0, cc0[r & 1]) CELLF(c70w0, aux0, cc0[r & 1])
                FMABLK(a3w1, aux1, cc1[r & 1]) CELLF(c70w1, aux1, cc1[r & 1])
            }
            // d=4
            if (r >= 4) {
                LOADROW(aux0, xp0, r - 4) LOADROW(aux1, xp1, r - 4)
                FMABLK(a4w0, aux0, cc0[r & 1])
                FMABLK(a4w1, aux1, cc1[r & 1])
            }
        }
    }
#undef LOADROW
#undef FMABLK
#undef CELLF

    // ===== Two-phase stage + flush (windows 0..63, then 64..127). =====
    float* obase = out + (size_t)blk * WPB * 64;
#pragma unroll
    for (int ph = 0; ph < 2; ++ph) {
        {
            float* slot = &lds[k * OSTRIDE];
            if (role == 0) {
                const float* A0 = ph ? a0w1 : a0w0;
                const float* A1 = ph ? a1w1 : a1w0;
                const float  C5 = ph ? c50w1 : c50w0;
                *reinterpret_cast<float4*>(slot + 24) = make_float4(A1[0], A1[1], A1[2], A1[3]);
                *reinterpret_cast<float4*>(slot + 28) = make_float4(A1[4], A1[5], A1[6], A1[7]);
                *reinterpret_cast<float4*>(slot + 32) = make_float4(A0[0], A0[1], A0[2], A0[3]);
                *reinterpret_cast<float4*>(slot + 36) = make_float4(A0[4], A0[5], A0[6], A0[7]);
                *reinterpret_cast<float4*>(slot + 40) = make_float4(C5,    A1[7], A1[6], A1[5]);
                *reinterpret_cast<float4*>(slot + 44) = make_float4(A1[4], A1[3], A1[2], A1[1]);
            } else {
                const float* A2 = ph ? a2w1 : a2w0;
                const float* A3 = ph ? a3w1 : a3w0;
                const float* A4 = ph ? a4w1 : a4w0;
                const float  C6 = ph ? c60w1 : c60w0;
                const float  C7 = ph ? c70w1 : c70w0;
                *reinterpret_cast<float4*>(slot + 0)  = make_float4(A4[0], A4[1], A4[2], A4[3]);
                *reinterpret_cast<float4*>(slot + 4)  = make_float4(A4[4], A4[5], A4[6], A4[7]);
                *reinterpret_cast<float4*>(slot + 8)  = make_float4(A3[0], A3[1], A3[2], A3[3]);
                *reinterpret_cast<float4*>(slot + 12) = make_float4(A3[4], A3[5], A3[6], A3[7]);
                *reinterpret_cast<float4*>(slot + 16) = make_float4(A2[0], A2[1], A2[2], A2[3]);
                *reinterpret_cast<float4*>(slot + 20) = make_float4(A2[4], A2[5], A2[6], A2[7]);
                *reinterpret_cast<float4*>(slot + 48) = make_float4(C6,    A2[7], A2[6], A2[5]);
                *reinterpret_cast<float4*>(slot + 52) = make_float4(A2[4], A2[3], A2[2], A2[1]);
                *reinterpret_cast<float4*>(slot + 56) = make_float4(C7,    A3[7], A3[6], A3[5]);
                *reinterpret_cast<float4*>(slot + 60) = make_float4(A3[4], A3[3], A3[2], A3[1]);
            }
        }
        __syncthreads();
        // Flush 64 windows x 16 float4 = 1024 slots, 8 per thread; each wave
        // store covers 1KB contiguous (4 complete 256B window regions).
#pragma unroll
        for (int kk = 0; kk < 8; ++kk) {
            const int flat4 = tid + kk * TPB;   // 0..1023
            const float4 v = *reinterpret_cast<const float4*>(
                &lds[(flat4 >> 4) * OSTRIDE + (flat4 & 15) * 4]);
            *reinterpret_cast<float4*>(obase + (size_t)ph * 64 * 64 + flat4 * 4) = v;
        }
        __syncthreads();  // WAR: protect slab before phase 1 restages
    }
}

extern "C" void kernel_launch(void* const* d_in, const int* in_sizes, int n_in,
                              void* d_out, int out_size, void* d_ws, size_t ws_size,
                              hipStream_t stream) {
    const float* x = (const float*)d_in[0];
    float* out = (float*)d_out;

    local_autocorr_kernel<<<NBLK, TPB, 0, stream>>>(x, out);
}